// Round 2
// baseline (221.598 us; speedup 1.0000x reference)
//
#include <hip/hip_runtime.h>

// ---------------------------------------------------------------------------
// RelativeSelfMultiheadAttn (Transformer-XL style) on gfx950.
// T=2048, B=2, D=512, NH=8, HD=64.
// Pipeline: wkernel -> gemm<0> (QKV) -> gemm<1> (R) -> attn -> gemm<2> (out).
// All internal tensors bf16 (threshold 7.47e-2 allows it), fp32 accumulate.
// ---------------------------------------------------------------------------

typedef float f32x4 __attribute__((ext_vector_type(4)));
typedef short bf16x8 __attribute__((ext_vector_type(8)));

#define NW 1314304
// Wf (fp32 weight sample) element offsets
#define OFF_INB  1310720
#define OFF_OUTB 1312256
#define OFF_POSB 1312768
#define OFF_RWB  1313280
#define OFF_RRB  1313792
// Wh (bf16 weight sample) element offsets
#define OFF_INW  0
#define OFF_OUTW 786432
#define OFF_POSW 1048576

#define L2E 1.44269504088896340736f

__device__ __forceinline__ unsigned short f2bf(float x) {
  unsigned u = __builtin_bit_cast(unsigned, x);
  u += 0x7fffu + ((u >> 16) & 1u);   // RNE
  return (unsigned short)(u >> 16);
}
__device__ __forceinline__ unsigned pk2(float lo, float hi) {
  return (unsigned)f2bf(lo) | ((unsigned)f2bf(hi) << 16);
}

// ---------------- weights: w = mu + softplus(rho)*eps ----------------------
__global__ void wkernel(const float* __restrict__ mu, const float* __restrict__ rho,
                        const float* __restrict__ eps, float* __restrict__ Wf,
                        unsigned short* __restrict__ Wh) {
  int i = blockIdx.x * 256 + threadIdx.x;
  if (i < NW) {
    float r = rho[i];
    float sp = (r > 20.f) ? r : log1pf(expf(r));
    float w = mu[i] + sp * eps[i];
    Wf[i] = w;
    Wh[i] = f2bf(w);
  }
}

// ---------------- generic 64x64x64-tile bf16 GEMM, C = A * W^T -------------
// MODE 0: A=input f32 [4096x512], W=in_w [1536x512]  -> scatter q_rw/q_rr/k/vT
// MODE 1: A=pos   f32 [2048x512], W=pos_w [512x512]  -> scatter rbuf
// MODE 2: A=attn  bf16 [4096x512], W=out_w [512x512] -> f32 d_out (+out_b)
template<int MODE>
__global__ __launch_bounds__(256, 2)
void gemm_kernel(const void* __restrict__ Ap, const unsigned short* __restrict__ Wp,
                 const float* __restrict__ Wf,
                 unsigned short* __restrict__ qrw, unsigned short* __restrict__ qrr,
                 unsigned short* __restrict__ kbuf, unsigned short* __restrict__ vT,
                 unsigned short* __restrict__ rbuf, float* __restrict__ outp)
{
  constexpr int Kd = 512;
  __shared__ __align__(16) unsigned short As[64 * 72];
  __shared__ __align__(16) unsigned short Bs[64 * 72];

  const int tid = threadIdx.x;
  const int wv = tid >> 6, lane = tid & 63, g = lane >> 4, cc = lane & 15;
  const int m0 = blockIdx.x * 64, n0 = blockIdx.y * 64;
  const int row = tid >> 2, q4 = tid & 3;

  f32x4 acc[4];
#pragma unroll
  for (int i = 0; i < 4; i++) { acc[i][0] = 0.f; acc[i][1] = 0.f; acc[i][2] = 0.f; acc[i][3] = 0.f; }

  for (int k0 = 0; k0 < Kd; k0 += 64) {
    if (MODE == 2) {
      const unsigned short* A = (const unsigned short*)Ap + (size_t)(m0 + row) * Kd + k0 + 16 * q4;
      uint4 u0 = *(const uint4*)A;
      uint4 u1 = *(const uint4*)(A + 8);
      *(uint4*)&As[row * 72 + 16 * q4] = u0;
      *(uint4*)&As[row * 72 + 16 * q4 + 8] = u1;
    } else {
      const float* A = (const float*)Ap + (size_t)(m0 + row) * Kd + k0 + 16 * q4;
      float4 f0 = *(const float4*)A;
      float4 f1 = *(const float4*)(A + 4);
      float4 f2 = *(const float4*)(A + 8);
      float4 f3 = *(const float4*)(A + 12);
      union { unsigned short s[8]; uint4 u; } p0, p1;
      p0.s[0] = f2bf(f0.x); p0.s[1] = f2bf(f0.y); p0.s[2] = f2bf(f0.z); p0.s[3] = f2bf(f0.w);
      p0.s[4] = f2bf(f1.x); p0.s[5] = f2bf(f1.y); p0.s[6] = f2bf(f1.z); p0.s[7] = f2bf(f1.w);
      p1.s[0] = f2bf(f2.x); p1.s[1] = f2bf(f2.y); p1.s[2] = f2bf(f2.z); p1.s[3] = f2bf(f2.w);
      p1.s[4] = f2bf(f3.x); p1.s[5] = f2bf(f3.y); p1.s[6] = f2bf(f3.z); p1.s[7] = f2bf(f3.w);
      *(uint4*)&As[row * 72 + 16 * q4] = p0.u;
      *(uint4*)&As[row * 72 + 16 * q4 + 8] = p1.u;
    }
    {
      const unsigned short* Bg = Wp + (size_t)(n0 + row) * Kd + k0 + 16 * q4;
      uint4 u0 = *(const uint4*)Bg;
      uint4 u1 = *(const uint4*)(Bg + 8);
      *(uint4*)&Bs[row * 72 + 16 * q4] = u0;
      *(uint4*)&Bs[row * 72 + 16 * q4 + 8] = u1;
    }
    __syncthreads();
#pragma unroll
    for (int ks = 0; ks < 2; ks++) {
      bf16x8 af = *(const bf16x8*)&As[(16 * wv + cc) * 72 + 32 * ks + 8 * g];
#pragma unroll
      for (int fn = 0; fn < 4; fn++) {
        bf16x8 bf = *(const bf16x8*)&Bs[(16 * fn + cc) * 72 + 32 * ks + 8 * g];
        acc[fn] = __builtin_amdgcn_mfma_f32_16x16x32_bf16(af, bf, acc[fn], 0, 0, 0);
      }
    }
    __syncthreads();
  }

  // epilogue: C row = m0+16*wv+4*g+r, col = n0+16*fn+cc
#pragma unroll
  for (int fn = 0; fn < 4; fn++) {
    const int col = n0 + 16 * fn + cc;
#pragma unroll
    for (int r = 0; r < 4; r++) {
      const int mrow = m0 + 16 * wv + 4 * g + r;
      float v = acc[fn][r];
      if (MODE == 0) {
        v += Wf[OFF_INB + col];
        const int sec = col >> 9;          // 0=q 1=k 2=v
        const int d = col & 511;
        const int nh = d >> 6, hd = d & 63;
        const int t = mrow >> 1, bb = mrow & 1;
        const size_t bi = ((size_t)(bb * 8 + nh) * 2048 + t) * 64 + hd;
        if (sec == 0) {
          qrw[bi] = f2bf(v + Wf[OFF_RWB + d]);
          qrr[bi] = f2bf(v + Wf[OFF_RRB + d]);
        } else if (sec == 1) {
          kbuf[bi] = f2bf(v);
        } else {
          vT[((size_t)(bb * 8 + nh) * 64 + hd) * 2048 + t] = f2bf(v);  // V transposed
        }
      } else if (MODE == 1) {
        v += Wf[OFF_POSB + col];
        const int nh = col >> 6, hd = col & 63;
        rbuf[((size_t)nh * 2048 + mrow) * 64 + hd] = f2bf(v);
      } else {
        outp[(size_t)mrow * 512 + col] = v + Wf[OFF_OUTB + col];
      }
    }
  }
}

// ---------------- fused relative flash attention ---------------------------
// Grid: 512 = (qtile desc)*16 + (b*8+n). Block: 256 (4 waves), wave owns 16
// queries x 64 keys per k-tile. Swapped MFMA orientation (St = K*Q^T) keeps
// softmax lane-local per query; P redistributed to PV A-frags via shfl.
// BD via band-GEMM G = Rband[79x64]*Qrr^T, gathered shifted through LDS.
__global__ __launch_bounds__(256, 2)
void attn_kernel(const unsigned short* __restrict__ qrw, const unsigned short* __restrict__ qrr,
                 const unsigned short* __restrict__ kb, const unsigned short* __restrict__ vt,
                 const unsigned short* __restrict__ rb, unsigned short* __restrict__ av)
{
  __shared__ __align__(16) unsigned short Ks[64 * 72];
  __shared__ __align__(16) unsigned short Vs[64 * 72];
  __shared__ __align__(16) unsigned short Rs[128 * 72];
  __shared__ __align__(16) float Gs[4 * 80 * 20];   // per-wave [80][20] f32

  const int tid = threadIdx.x;
  const int wv = tid >> 6, lane = tid & 63, g = lane >> 4, cc = lane & 15;
  const int qt = 31 - (int)(blockIdx.x >> 4);        // heavy tiles first
  const int bn = blockIdx.x & 15;
  const int nh = bn & 7, bb = bn >> 3;
  const int i0 = qt * 64;
  const int i0g = i0 + wv * 16;

  const size_t qko = (size_t)bn * 2048 * 64;
  const size_t ro = (size_t)nh * 2048 * 64;

  // hoisted Q fragments (B-operand: lane holds Q[i0g+cc][d-slice])
  bf16x8 qw[2], qr[2];
#pragma unroll
  for (int ks = 0; ks < 2; ks++) {
    qw[ks] = *(const bf16x8*)&qrw[qko + (size_t)(i0g + cc) * 64 + 32 * ks + 8 * g];
    qr[ks] = *(const bf16x8*)&qrr[qko + (size_t)(i0g + cc) * 64 + 32 * ks + 8 * g];
  }

  float m_run = -3.0e38f, l_run = 0.f;
  f32x4 o[4];
#pragma unroll
  for (int i = 0; i < 4; i++) { o[i][0] = 0.f; o[i][1] = 0.f; o[i][2] = 0.f; o[i][3] = 0.f; }

  const int srow = tid >> 2, sq = tid & 3;
  const int rrow = tid >> 1, rhalf = tid & 1;
  float* Gw = &Gs[wv * 1600];
  const int rbase = 48 - 16 * wv;

  for (int kt = 0; kt <= qt; kt++) {
    const int j0 = kt * 64;
    // ---- stage K [64][64], Vt [64hd][64t], Rband [128][64] ----
    {
      const unsigned short* kp = &kb[qko + (size_t)(j0 + srow) * 64 + 16 * sq];
      uint4 a0 = *(const uint4*)kp, a1 = *(const uint4*)(kp + 8);
      *(uint4*)&Ks[srow * 72 + 16 * sq] = a0;
      *(uint4*)&Ks[srow * 72 + 16 * sq + 8] = a1;
      const unsigned short* vp = &vt[qko + (size_t)srow * 2048 + j0 + 16 * sq];
      uint4 b0 = *(const uint4*)vp, b1 = *(const uint4*)(vp + 8);
      *(uint4*)&Vs[srow * 72 + 16 * sq] = b0;
      *(uint4*)&Vs[srow * 72 + 16 * sq + 8] = b1;
      int u = 1984 - i0 + j0 + rrow; if (u > 2047) u = 2047;   // clamped rows are masked
      const unsigned short* rp = &rb[ro + (size_t)u * 64 + 32 * rhalf];
      uint4 c0 = *(const uint4*)rp, c1 = *(const uint4*)(rp + 8);
      uint4 c2 = *(const uint4*)(rp + 16), c3 = *(const uint4*)(rp + 24);
      unsigned short* rd = &Rs[rrow * 72 + 32 * rhalf];
      *(uint4*)rd = c0; *(uint4*)(rd + 8) = c1; *(uint4*)(rd + 16) = c2; *(uint4*)(rd + 24) = c3;
    }
    __syncthreads();

    // ---- St[jj,ii] = sum_d K[j0+jj,d] * Qrw[i0g+ii,d] ----
    f32x4 st[4];
#pragma unroll
    for (int i = 0; i < 4; i++) { st[i][0] = 0.f; st[i][1] = 0.f; st[i][2] = 0.f; st[i][3] = 0.f; }
#pragma unroll
    for (int ks = 0; ks < 2; ks++) {
#pragma unroll
      for (int fm = 0; fm < 4; fm++) {
        bf16x8 ka = *(const bf16x8*)&Ks[(16 * fm + cc) * 72 + 32 * ks + 8 * g];
        st[fm] = __builtin_amdgcn_mfma_f32_16x16x32_bf16(ka, qw[ks], st[fm], 0, 0, 0);
      }
    }
    // ---- G[c,ii] = sum_d Rband[rbase+c,d] * Qrr[i0g+ii,d], c in [0,79) ----
    f32x4 gt[5];
#pragma unroll
    for (int i = 0; i < 5; i++) { gt[i][0] = 0.f; gt[i][1] = 0.f; gt[i][2] = 0.f; gt[i][3] = 0.f; }
#pragma unroll
    for (int ks = 0; ks < 2; ks++) {
#pragma unroll
      for (int fm = 0; fm < 5; fm++) {
        bf16x8 ra = *(const bf16x8*)&Rs[(rbase + 16 * fm + cc) * 72 + 32 * ks + 8 * g];
        gt[fm] = __builtin_amdgcn_mfma_f32_16x16x32_bf16(ra, qr[ks], gt[fm], 0, 0, 0);
      }
    }
#pragma unroll
    for (int fm = 0; fm < 5; fm++)
#pragma unroll
      for (int r = 0; r < 4; r++)
        Gw[(16 * fm + 4 * g + r) * 20 + cc] = gt[fm][r];   // odd stride 20 -> conflict-free shifted read

    // ---- combine + mask + online softmax (state lives at query ii == cc) ----
    float p[4][4];
    float tm = -3.0e38f;
    const bool diag = (kt == qt);
#pragma unroll
    for (int fm = 0; fm < 4; fm++) {
#pragma unroll
      for (int r = 0; r < 4; r++) {
        const int jj = 16 * fm + 4 * g + r;
        float bd = Gw[(jj - cc + 15) * 20 + cc];           // rel-shift gather
        float sv = (st[fm][r] + bd) * 0.125f;
        if (diag && (jj > cc + 16 * wv)) sv = -3.0e38f;    // causal mask
        p[fm][r] = sv;
        tm = fmaxf(tm, sv);
      }
    }
    tm = fmaxf(tm, __shfl_xor(tm, 16));
    tm = fmaxf(tm, __shfl_xor(tm, 32));
    const float m_new = fmaxf(m_run, tm);
    const float sc = exp2f((m_run - m_new) * L2E);
    float ps = 0.f;
#pragma unroll
    for (int fm = 0; fm < 4; fm++)
#pragma unroll
      for (int r = 0; r < 4; r++) {
        float pv = exp2f((p[fm][r] - m_new) * L2E);
        p[fm][r] = pv;
        ps += pv;
      }
    ps += __shfl_xor(ps, 16);
    ps += __shfl_xor(ps, 32);
    l_run = l_run * sc + ps;
    m_run = m_new;

    // rescale O (O rows are ii = 4g+r; state at lane ii)
    float scr[4];
#pragma unroll
    for (int r = 0; r < 4; r++) scr[r] = __shfl(sc, 4 * g + r);
#pragma unroll
    for (int fn = 0; fn < 4; fn++)
#pragma unroll
      for (int r = 0; r < 4; r++) o[fn][r] *= scr[r];

    // pack P to bf16 pairs and shfl-redistribute into PV A-frags
    unsigned u01[4], u23[4];
#pragma unroll
    for (int fm = 0; fm < 4; fm++) {
      u01[fm] = pk2(p[fm][0], p[fm][1]);
      u23[fm] = pk2(p[fm][2], p[fm][3]);
    }
    bf16x8 pa[2];
#pragma unroll
    for (int ks = 0; ks < 2; ks++) {
      union { unsigned u[4]; bf16x8 v; } pw;
#pragma unroll
      for (int j = 0; j < 4; j++) {
        const int srcl = (2 * (g & 1) + (j >> 1)) * 16 + cc;
        unsigned v0 = __shfl((j & 1) ? u23[2 * ks] : u01[2 * ks], srcl);
        unsigned v1 = __shfl((j & 1) ? u23[2 * ks + 1] : u01[2 * ks + 1], srcl);
        pw.u[j] = (g >> 1) ? v1 : v0;
      }
      pa[ks] = pw.v;
    }
    // ---- O[ii,hd] += P[ii,jj] * V[j0+jj,hd] ----
#pragma unroll
    for (int ks = 0; ks < 2; ks++) {
#pragma unroll
      for (int fn = 0; fn < 4; fn++) {
        bf16x8 vb = *(const bf16x8*)&Vs[(16 * fn + cc) * 72 + 32 * ks + 8 * g];
        o[fn] = __builtin_amdgcn_mfma_f32_16x16x32_bf16(pa[ks], vb, o[fn], 0, 0, 0);
      }
    }
    __syncthreads();
  }

  // ---- epilogue: normalize and store attn_vec[t][b][n][hd] (bf16) ----
  const float inv = 1.0f / l_run;
  float invr[4];
#pragma unroll
  for (int r = 0; r < 4; r++) invr[r] = __shfl(inv, 4 * g + r);
#pragma unroll
  for (int fn = 0; fn < 4; fn++) {
    const int hd = 16 * fn + cc;
#pragma unroll
    for (int r = 0; r < 4; r++) {
      const int irow = i0g + 4 * g + r;
      av[((size_t)(irow * 2 + bb) * 8 + nh) * 64 + hd] = f2bf(o[fn][r] * invr[r]);
    }
  }
}

// ---------------------------------------------------------------------------
extern "C" void kernel_launch(void* const* d_in, const int* in_sizes, int n_in,
                              void* d_out, int out_size, void* d_ws, size_t ws_size,
                              hipStream_t stream) {
  const float* input = (const float*)d_in[0];
  const float* pos   = (const float*)d_in[1];
  // d_in[2] attn_mask: known causal triu(1), not read
  const float* mu  = (const float*)d_in[3];
  const float* rho = (const float*)d_in[4];
  const float* eps = (const float*)d_in[5];
  float* out = (float*)d_out;

  // workspace layout (bytes); total ~29.6 MB
  char* ws = (char*)d_ws;
  float* Wf = (float*)ws;                                   // 5,257,216
  unsigned short* Wh = (unsigned short*)(ws + 5257216);     // 2,628,608
  char* b2 = ws + 7885824;
  unsigned short* qrw  = (unsigned short*)(b2);             // 4 MB each
  unsigned short* qrr  = (unsigned short*)(b2 + 4194304);
  unsigned short* kbuf = (unsigned short*)(b2 + 8388608);
  unsigned short* vT   = (unsigned short*)(b2 + 12582912);
  unsigned short* rbuf = (unsigned short*)(b2 + 16777216);  // 2 MB
  unsigned short* av   = (unsigned short*)(b2 + 18874368);  // 4 MB

  wkernel<<<dim3(5134), dim3(256), 0, stream>>>(mu, rho, eps, Wf, Wh);
  gemm_kernel<0><<<dim3(64, 24), dim3(256), 0, stream>>>(
      (const void*)input, Wh + OFF_INW, Wf, qrw, qrr, kbuf, vT, rbuf, out);
  gemm_kernel<1><<<dim3(32, 8), dim3(256), 0, stream>>>(
      (const void*)pos, Wh + OFF_POSW, Wf, qrw, qrr, kbuf, vT, rbuf, out);
  attn_kernel<<<dim3(512), dim3(256), 0, stream>>>(qrw, qrr, kbuf, vT, rbuf, av);
  gemm_kernel<2><<<dim3(64, 8), dim3(256), 0, stream>>>(
      (const void*)av, Wh + OFF_OUTW, Wf, qrw, qrr, kbuf, vT, rbuf, out);
}

// Round 3
// 173.950 us; speedup vs baseline: 1.2739x; 1.2739x over previous
//
#include <hip/hip_runtime.h>

// ---------------------------------------------------------------------------
// RelativeSelfMultiheadAttn (Transformer-XL style) on gfx950.
// T=2048, B=2, D=512, NH=8, HD=64.
// Pipeline: prep -> gemm01 (QKV+R) -> attn -> gemmO (out).
// Internal tensors bf16 (threshold 7.47e-2; round-2 absmax 0.0156), fp32 acc.
// Round-3: balanced q-tile pairing (CU pairing bx/bx+256 -> 33 iters/CU),
// T14 reg-prefetch staging in attn + gemms, R ring buffer, setprio, bf16
// pre-cast of activations, merged QKV+R launch.
// ---------------------------------------------------------------------------

typedef float f32x4 __attribute__((ext_vector_type(4)));
typedef short bf16x8 __attribute__((ext_vector_type(8)));

#define NW 1314304
// flat-w element offsets (weights in Wh bf16; biases in Bf f32)
#define OFF_INB  1310720
#define OFF_INW  0
#define OFF_OUTW 786432
#define OFF_POSW 1048576
// bias-buffer local offsets (floats)
#define BB_IN  0
#define BB_OUT 1536
#define BB_POS 2048
#define BB_RW  2560
#define BB_RR  3072

#define L2E 1.44269504088896340736f

__device__ __forceinline__ unsigned short f2bf(float x) {
  unsigned u = __builtin_bit_cast(unsigned, x);
  u += 0x7fffu + ((u >> 16) & 1u);   // RNE
  return (unsigned short)(u >> 16);
}
__device__ __forceinline__ unsigned pk2(float lo, float hi) {
  return (unsigned)f2bf(lo) | ((unsigned)f2bf(hi) << 16);
}

// ---------------- prep: weight sample + activation bf16 cast ---------------
// blocks [0,1284): w = mu + softplus(rho)*eps -> Wh bf16 (+ bias tail -> Bf f32)
// blocks [1284,3332): input f32 -> bf16   (2,097,152 elems)
// blocks [3332,4356): pos   f32 -> bf16   (1,048,576 elems)
__global__ void prep_kernel(const float* __restrict__ mu, const float* __restrict__ rho,
                            const float* __restrict__ eps,
                            const float* __restrict__ input, const float* __restrict__ pos,
                            unsigned short* __restrict__ Wh, float* __restrict__ Bf,
                            unsigned short* __restrict__ inH, unsigned short* __restrict__ posH) {
  const int bx = blockIdx.x;
  if (bx < 1284) {
    int i = (bx * 256 + threadIdx.x) * 4;
    if (i < NW) {
      float4 m = *(const float4*)&mu[i];
      float4 r = *(const float4*)&rho[i];
      float4 e = *(const float4*)&eps[i];
      float w0 = m.x + ((r.x > 20.f) ? r.x : log1pf(expf(r.x))) * e.x;
      float w1 = m.y + ((r.y > 20.f) ? r.y : log1pf(expf(r.y))) * e.y;
      float w2 = m.z + ((r.z > 20.f) ? r.z : log1pf(expf(r.z))) * e.z;
      float w3 = m.w + ((r.w > 20.f) ? r.w : log1pf(expf(r.w))) * e.w;
      union { unsigned short s[4]; uint2 u; } p;
      p.s[0] = f2bf(w0); p.s[1] = f2bf(w1); p.s[2] = f2bf(w2); p.s[3] = f2bf(w3);
      *(uint2*)&Wh[i] = p.u;
      if (i >= OFF_INB) {
        float4 b; b.x = w0; b.y = w1; b.z = w2; b.w = w3;
        *(float4*)&Bf[i - OFF_INB] = b;
      }
    }
  } else if (bx < 3332) {
    int i = ((bx - 1284) * 256 + threadIdx.x) * 4;
    float4 v = *(const float4*)&input[i];
    union { unsigned short s[4]; uint2 u; } p;
    p.s[0] = f2bf(v.x); p.s[1] = f2bf(v.y); p.s[2] = f2bf(v.z); p.s[3] = f2bf(v.w);
    *(uint2*)&inH[i] = p.u;
  } else {
    int i = ((bx - 3332) * 256 + threadIdx.x) * 4;
    float4 v = *(const float4*)&pos[i];
    union { unsigned short s[4]; uint2 u; } p;
    p.s[0] = f2bf(v.x); p.s[1] = f2bf(v.y); p.s[2] = f2bf(v.z); p.s[3] = f2bf(v.w);
    *(uint2*)&posH[i] = p.u;
  }
}

// ---------------- shared 64x64x512 bf16 tile core (C = A * W^T) ------------
// T14: prefetch next k-slab into regs before compute, write after barrier.
__device__ __forceinline__ void gemm_loop(const unsigned short* __restrict__ A,
                                          const unsigned short* __restrict__ B,
                                          unsigned short* As, unsigned short* Bs,
                                          f32x4 (&acc)[4]) {
  const int tid = threadIdx.x;
  const int wv = tid >> 6, lane = tid & 63, g = lane >> 4, cc = lane & 15;
  const int row = tid >> 2, q4 = tid & 3;
  const unsigned short* Ap = A + (size_t)row * 512 + 16 * q4;
  const unsigned short* Bp = B + (size_t)row * 512 + 16 * q4;

  *(uint4*)&As[row * 72 + 16 * q4]     = *(const uint4*)Ap;
  *(uint4*)&As[row * 72 + 16 * q4 + 8] = *(const uint4*)(Ap + 8);
  *(uint4*)&Bs[row * 72 + 16 * q4]     = *(const uint4*)Bp;
  *(uint4*)&Bs[row * 72 + 16 * q4 + 8] = *(const uint4*)(Bp + 8);
  __syncthreads();

  for (int it = 0; it < 8; it++) {
    uint4 a0, a1, b0, b1;
    const bool pf = (it < 7);
    if (pf) {
      const unsigned short* An = Ap + 64 * (it + 1);
      const unsigned short* Bn = Bp + 64 * (it + 1);
      a0 = *(const uint4*)An; a1 = *(const uint4*)(An + 8);
      b0 = *(const uint4*)Bn; b1 = *(const uint4*)(Bn + 8);
    }
    __builtin_amdgcn_s_setprio(1);
#pragma unroll
    for (int ks = 0; ks < 2; ks++) {
      bf16x8 af = *(const bf16x8*)&As[(16 * wv + cc) * 72 + 32 * ks + 8 * g];
#pragma unroll
      for (int fn = 0; fn < 4; fn++) {
        bf16x8 bf = *(const bf16x8*)&Bs[(16 * fn + cc) * 72 + 32 * ks + 8 * g];
        acc[fn] = __builtin_amdgcn_mfma_f32_16x16x32_bf16(af, bf, acc[fn], 0, 0, 0);
      }
    }
    __builtin_amdgcn_s_setprio(0);
    __syncthreads();
    if (pf) {
      *(uint4*)&As[row * 72 + 16 * q4]     = a0;
      *(uint4*)&As[row * 72 + 16 * q4 + 8] = a1;
      *(uint4*)&Bs[row * 72 + 16 * q4]     = b0;
      *(uint4*)&Bs[row * 72 + 16 * q4 + 8] = b1;
    }
    __syncthreads();
  }
}

// ---------------- gemm01: QKV projection (1536 blocks) + R proj (256) ------
__global__ __launch_bounds__(256, 2)
void gemm01_kernel(const unsigned short* __restrict__ inH, const unsigned short* __restrict__ posH,
                   const unsigned short* __restrict__ Wh, const float* __restrict__ Bf,
                   unsigned short* __restrict__ qrw, unsigned short* __restrict__ qrr,
                   unsigned short* __restrict__ kbuf, unsigned short* __restrict__ vT,
                   unsigned short* __restrict__ rbuf) {
  __shared__ __align__(16) unsigned short As[64 * 72];
  __shared__ __align__(16) unsigned short Bs[64 * 72];
  const int bx = blockIdx.x;
  const int tid = threadIdx.x;
  const int wv = tid >> 6, lane = tid & 63, g = lane >> 4, cc = lane & 15;

  const bool isR = (bx >= 1536);
  int m0, n0;
  const unsigned short *A, *W;
  if (!isR) {
    m0 = (bx & 63) << 6; n0 = (bx >> 6) << 6;
    A = inH + (size_t)m0 * 512;  W = Wh + OFF_INW + (size_t)n0 * 512;
  } else {
    const int t = bx - 1536;
    m0 = (t & 31) << 6; n0 = (t >> 5) << 6;
    A = posH + (size_t)m0 * 512; W = Wh + OFF_POSW + (size_t)n0 * 512;
  }

  f32x4 acc[4];
#pragma unroll
  for (int i = 0; i < 4; i++) { acc[i][0] = 0.f; acc[i][1] = 0.f; acc[i][2] = 0.f; acc[i][3] = 0.f; }
  gemm_loop(A, W, As, Bs, acc);

#pragma unroll
  for (int fn = 0; fn < 4; fn++) {
    const int col = n0 + 16 * fn + cc;
#pragma unroll
    for (int r = 0; r < 4; r++) {
      const int mrow = m0 + 16 * wv + 4 * g + r;
      float v = acc[fn][r];
      if (!isR) {
        v += Bf[BB_IN + col];
        const int sec = col >> 9;          // 0=q 1=k 2=v
        const int d = col & 511;
        const int nh = d >> 6, hd = d & 63;
        const int t = mrow >> 1, bb = mrow & 1;
        const size_t bi = ((size_t)(bb * 8 + nh) * 2048 + t) * 64 + hd;
        if (sec == 0) {
          qrw[bi] = f2bf(v + Bf[BB_RW + d]);
          qrr[bi] = f2bf(v + Bf[BB_RR + d]);
        } else if (sec == 1) {
          kbuf[bi] = f2bf(v);
        } else {
          vT[((size_t)(bb * 8 + nh) * 64 + hd) * 2048 + t] = f2bf(v);  // V transposed
        }
      } else {
        v += Bf[BB_POS + col];
        rbuf[((size_t)(col >> 6) * 2048 + mrow) * 64 + (col & 63)] = f2bf(v);
      }
    }
  }
}

// ---------------- gemmO: out projection -> f32 d_out -----------------------
__global__ __launch_bounds__(256, 2)
void gemmO_kernel(const unsigned short* __restrict__ av, const unsigned short* __restrict__ W,
                  const float* __restrict__ Bf, float* __restrict__ outp) {
  __shared__ __align__(16) unsigned short As[64 * 72];
  __shared__ __align__(16) unsigned short Bs[64 * 72];
  const int bx = blockIdx.x;
  const int tid = threadIdx.x;
  const int wv = tid >> 6, lane = tid & 63, g = lane >> 4, cc = lane & 15;
  const int m0 = (bx & 63) << 6, n0 = (bx >> 6) << 6;

  f32x4 acc[4];
#pragma unroll
  for (int i = 0; i < 4; i++) { acc[i][0] = 0.f; acc[i][1] = 0.f; acc[i][2] = 0.f; acc[i][3] = 0.f; }
  gemm_loop(av + (size_t)m0 * 512, W + (size_t)n0 * 512, As, Bs, acc);

#pragma unroll
  for (int fn = 0; fn < 4; fn++) {
    const int col = n0 + 16 * fn + cc;
#pragma unroll
    for (int r = 0; r < 4; r++) {
      const int mrow = m0 + 16 * wv + 4 * g + r;
      outp[(size_t)mrow * 512 + col] = acc[fn][r] + Bf[BB_OUT + col];
    }
  }
}

// ---------------- fused relative flash attention ---------------------------
// 512 blocks: bx<256 -> qt=31-(idx>>4) (heavy), bx>=256 -> qt=idx>>4 (light);
// under breadth-first dispatch bx and bx+256 share a CU -> 33 iters each CU.
// Per wave: 16 queries x 64 keys/tile; swapped St = K*Q^T keeps softmax
// lane-local; BD via band-GEMM on an R ring buffer (64 new rows/iter);
// T14 reg-prefetch of K/V/R for kt+1 under compute(kt).
__global__ __launch_bounds__(256, 2)
void attn_kernel(const unsigned short* __restrict__ qrw, const unsigned short* __restrict__ qrr,
                 const unsigned short* __restrict__ kb, const unsigned short* __restrict__ vt,
                 const unsigned short* __restrict__ rb, unsigned short* __restrict__ av)
{
  __shared__ __align__(16) unsigned short Ks[64 * 72];
  __shared__ __align__(16) unsigned short Vs[64 * 72];
  __shared__ __align__(16) unsigned short Rs[128 * 72];   // ring: slot = u & 127
  __shared__ __align__(16) float Gs[4 * 80 * 20];         // per-wave [80][20] f32

  const int tid = threadIdx.x;
  const int wv = tid >> 6, lane = tid & 63, g = lane >> 4, cc = lane & 15;
  const int bx = (int)blockIdx.x;
  const int idx = bx & 255;
  const int qt = (bx >> 8) ? (idx >> 4) : (31 - (idx >> 4));
  const int bn = idx & 15;
  const int nh = bn & 7, bb = bn >> 3;
  const int i0 = qt * 64;
  const int i0g = i0 + wv * 16;
  const int w0base = 1984 - i0;                // R window base at kt=0

  const size_t qko = (size_t)bn * 2048 * 64;
  const size_t ro = (size_t)nh * 2048 * 64;

  // hoisted Q fragments (B-operand: lane holds Q[i0g+cc][d-slice])
  bf16x8 qw[2], qr[2];
#pragma unroll
  for (int ks = 0; ks < 2; ks++) {
    qw[ks] = *(const bf16x8*)&qrw[qko + (size_t)(i0g + cc) * 64 + 32 * ks + 8 * g];
    qr[ks] = *(const bf16x8*)&qrr[qko + (size_t)(i0g + cc) * 64 + 32 * ks + 8 * g];
  }

  float m_run = -3.0e38f, l_run = 0.f;
  f32x4 o[4];
#pragma unroll
  for (int i = 0; i < 4; i++) { o[i][0] = 0.f; o[i][1] = 0.f; o[i][2] = 0.f; o[i][3] = 0.f; }

  const int srow = tid >> 2, sq = tid & 3;     // K/V/R-loop: 4 thr/row, 16 shorts
  const int rrow = tid >> 1, rhalf = tid & 1;  // R prologue: 2 thr/row, 32 shorts
  float* Gw = &Gs[wv * 1600];
  const int rbase = 48 - 16 * wv;

  // ---- prologue: stage kt=0 K/V + full 128-row R window ----
  {
    const unsigned short* kp = &kb[qko + (size_t)srow * 64 + 16 * sq];
    *(uint4*)&Ks[srow * 72 + 16 * sq]     = *(const uint4*)kp;
    *(uint4*)&Ks[srow * 72 + 16 * sq + 8] = *(const uint4*)(kp + 8);
    const unsigned short* vp = &vt[qko + (size_t)srow * 2048 + 16 * sq];
    *(uint4*)&Vs[srow * 72 + 16 * sq]     = *(const uint4*)vp;
    *(uint4*)&Vs[srow * 72 + 16 * sq + 8] = *(const uint4*)(vp + 8);
    const int u0 = w0base + rrow;
    const int uc0 = u0 > 2047 ? 2047 : u0;     // clamped rows only feed masked entries
    const unsigned short* rp = &rb[ro + (size_t)uc0 * 64 + 32 * rhalf];
    unsigned short* rd = &Rs[(u0 & 127) * 72 + 32 * rhalf];
    *(uint4*)rd        = *(const uint4*)rp;
    *(uint4*)(rd + 8)  = *(const uint4*)(rp + 8);
    *(uint4*)(rd + 16) = *(const uint4*)(rp + 16);
    *(uint4*)(rd + 24) = *(const uint4*)(rp + 24);
  }
  __syncthreads();

  for (int kt = 0; kt <= qt; kt++) {
    const int j0 = kt * 64;
    const int w0k = w0base + j0;
    const bool pf = (kt < qt);

    // ---- T14: issue kt+1 loads into regs (latency hides under compute) ----
    uint4 ka0, ka1, va0, va1, ra0, ra1;
    int rslot = 0;
    if (pf) {
      const unsigned short* kp = &kb[qko + (size_t)(j0 + 64 + srow) * 64 + 16 * sq];
      ka0 = *(const uint4*)kp; ka1 = *(const uint4*)(kp + 8);
      const unsigned short* vp = &vt[qko + (size_t)srow * 2048 + j0 + 64 + 16 * sq];
      va0 = *(const uint4*)vp; va1 = *(const uint4*)(vp + 8);
      const int unew = w0k + 128 + (tid >> 2);  // 64 new ring rows
      rslot = unew & 127;
      const int uc = unew > 2047 ? 2047 : unew;
      const unsigned short* rp = &rb[ro + (size_t)uc * 64 + 16 * sq];
      ra0 = *(const uint4*)rp; ra1 = *(const uint4*)(rp + 8);
    }

    // ---- St[jj,ii] = sum_d K[j0+jj,d] * Qrw[i0g+ii,d] ----
    f32x4 st[4];
#pragma unroll
    for (int i = 0; i < 4; i++) { st[i][0] = 0.f; st[i][1] = 0.f; st[i][2] = 0.f; st[i][3] = 0.f; }
    __builtin_amdgcn_s_setprio(1);
#pragma unroll
    for (int ks = 0; ks < 2; ks++) {
#pragma unroll
      for (int fm = 0; fm < 4; fm++) {
        bf16x8 ka = *(const bf16x8*)&Ks[(16 * fm + cc) * 72 + 32 * ks + 8 * g];
        st[fm] = __builtin_amdgcn_mfma_f32_16x16x32_bf16(ka, qw[ks], st[fm], 0, 0, 0);
      }
    }
    // ---- G[c,ii] = sum_d R[ring(w0k+rbase+c),d] * Qrr[i0g+ii,d], c in [0,80) ----
    f32x4 gt[5];
#pragma unroll
    for (int i = 0; i < 5; i++) { gt[i][0] = 0.f; gt[i][1] = 0.f; gt[i][2] = 0.f; gt[i][3] = 0.f; }
    const int rr0 = w0k + rbase + cc;
#pragma unroll
    for (int ks = 0; ks < 2; ks++) {
#pragma unroll
      for (int fm = 0; fm < 5; fm++) {
        const int rrw = (rr0 + 16 * fm) & 127;
        bf16x8 ra = *(const bf16x8*)&Rs[rrw * 72 + 32 * ks + 8 * g];
        gt[fm] = __builtin_amdgcn_mfma_f32_16x16x32_bf16(ra, qr[ks], gt[fm], 0, 0, 0);
      }
    }
    __builtin_amdgcn_s_setprio(0);
#pragma unroll
    for (int fm = 0; fm < 5; fm++)
#pragma unroll
      for (int r = 0; r < 4; r++)
        Gw[(16 * fm + 4 * g + r) * 20 + cc] = gt[fm][r];   // stride 20 -> 2-way max

    // ---- combine + mask + online softmax (state lives at query ii == cc) ----
    float p[4][4];
    float tm = -3.0e38f;
    const bool diag = (kt == qt);
#pragma unroll
    for (int fm = 0; fm < 4; fm++) {
#pragma unroll
      for (int r = 0; r < 4; r++) {
        const int jj = 16 * fm + 4 * g + r;
        float bd = Gw[(jj - cc + 15) * 20 + cc];           // rel-shift gather
        float sv = (st[fm][r] + bd) * 0.125f;
        if (diag && (jj > cc + 16 * wv)) sv = -3.0e38f;    // causal mask
        p[fm][r] = sv;
        tm = fmaxf(tm, sv);
      }
    }
    tm = fmaxf(tm, __shfl_xor(tm, 16));
    tm = fmaxf(tm, __shfl_xor(tm, 32));
    const float m_new = fmaxf(m_run, tm);
    const float sc = exp2f((m_run - m_new) * L2E);
    float ps = 0.f;
#pragma unroll
    for (int fm = 0; fm < 4; fm++)
#pragma unroll
      for (int r = 0; r < 4; r++) {
        float pv = exp2f((p[fm][r] - m_new) * L2E);
        p[fm][r] = pv;
        ps += pv;
      }
    ps += __shfl_xor(ps, 16);
    ps += __shfl_xor(ps, 32);
    l_run = l_run * sc + ps;
    m_run = m_new;

    // rescale O (O rows are ii = 4g+r; state at lane ii)
    float scr[4];
#pragma unroll
    for (int r = 0; r < 4; r++) scr[r] = __shfl(sc, 4 * g + r);
#pragma unroll
    for (int fn = 0; fn < 4; fn++)
#pragma unroll
      for (int r = 0; r < 4; r++) o[fn][r] *= scr[r];

    // pack P to bf16 pairs and shfl-redistribute into PV A-frags
    unsigned u01[4], u23[4];
#pragma unroll
    for (int fm = 0; fm < 4; fm++) {
      u01[fm] = pk2(p[fm][0], p[fm][1]);
      u23[fm] = pk2(p[fm][2], p[fm][3]);
    }
    bf16x8 pa[2];
#pragma unroll
    for (int ks = 0; ks < 2; ks++) {
      union { unsigned u[4]; bf16x8 v; } pw;
#pragma unroll
      for (int j = 0; j < 4; j++) {
        const int srcl = (2 * (g & 1) + (j >> 1)) * 16 + cc;
        unsigned v0 = __shfl((j & 1) ? u23[2 * ks] : u01[2 * ks], srcl);
        unsigned v1 = __shfl((j & 1) ? u23[2 * ks + 1] : u01[2 * ks + 1], srcl);
        pw.u[j] = (g >> 1) ? v1 : v0;
      }
      pa[ks] = pw.v;
    }
    // ---- O[ii,hd] += P[ii,jj] * V[j0+jj,hd] ----
    __builtin_amdgcn_s_setprio(1);
#pragma unroll
    for (int ks = 0; ks < 2; ks++) {
#pragma unroll
      for (int fn = 0; fn < 4; fn++) {
        bf16x8 vb = *(const bf16x8*)&Vs[(16 * fn + cc) * 72 + 32 * ks + 8 * g];
        o[fn] = __builtin_amdgcn_mfma_f32_16x16x32_bf16(pa[ks], vb, o[fn], 0, 0, 0);
      }
    }
    __builtin_amdgcn_s_setprio(0);

    __syncthreads();           // all waves done reading Ks/Vs/Rs
    if (pf) {
      *(uint4*)&Ks[srow * 72 + 16 * sq]     = ka0;
      *(uint4*)&Ks[srow * 72 + 16 * sq + 8] = ka1;
      *(uint4*)&Vs[srow * 72 + 16 * sq]     = va0;
      *(uint4*)&Vs[srow * 72 + 16 * sq + 8] = va1;
      unsigned short* rd = &Rs[rslot * 72 + 16 * sq];
      *(uint4*)rd       = ra0;
      *(uint4*)(rd + 8) = ra1;
    }
    __syncthreads();           // kt+1 tiles ready
  }

  // ---- epilogue: normalize and store attn_vec[t][b][n][hd] (bf16) ----
  const float inv = 1.0f / l_run;
  float invr[4];
#pragma unroll
  for (int r = 0; r < 4; r++) invr[r] = __shfl(inv, 4 * g + r);
#pragma unroll
  for (int fn = 0; fn < 4; fn++) {
    const int hd = 16 * fn + cc;
#pragma unroll
    for (int r = 0; r < 4; r++) {
      const int irow = i0g + 4 * g + r;
      av[((size_t)(irow * 2 + bb) * 8 + nh) * 64 + hd] = f2bf(o[fn][r] * invr[r]);
    }
  }
}

// ---------------------------------------------------------------------------
extern "C" void kernel_launch(void* const* d_in, const int* in_sizes, int n_in,
                              void* d_out, int out_size, void* d_ws, size_t ws_size,
                              hipStream_t stream) {
  const float* input = (const float*)d_in[0];
  const float* pos   = (const float*)d_in[1];
  // d_in[2] attn_mask: known causal triu(1), not read
  const float* mu  = (const float*)d_in[3];
  const float* rho = (const float*)d_in[4];
  const float* eps = (const float*)d_in[5];
  float* out = (float*)d_out;

  // workspace layout (bytes); total 27.8 MB. av aliases inH (dead after gemm01).
  char* ws = (char*)d_ws;
  unsigned short* Wh   = (unsigned short*)ws;                 // 2,628,608
  float*          Bf   = (float*)(ws + 2628608);              // 14,336
  unsigned short* inH  = (unsigned short*)(ws + 2642944);     // 4,194,304
  unsigned short* posH = (unsigned short*)(ws + 6837248);     // 2,097,152
  unsigned short* qrw  = (unsigned short*)(ws + 8934400);     // 4 MB each
  unsigned short* qrr  = (unsigned short*)(ws + 13128704);
  unsigned short* kbuf = (unsigned short*)(ws + 17323008);
  unsigned short* vT   = (unsigned short*)(ws + 21517312);
  unsigned short* rbuf = (unsigned short*)(ws + 25711616);    // 2 MB
  unsigned short* av   = inH;                                 // alias

  prep_kernel<<<dim3(4356), dim3(256), 0, stream>>>(mu, rho, eps, input, pos, Wh, Bf, inH, posH);
  gemm01_kernel<<<dim3(1792), dim3(256), 0, stream>>>(inH, posH, Wh, Bf, qrw, qrr, kbuf, vT, rbuf);
  attn_kernel<<<dim3(512), dim3(256), 0, stream>>>(qrw, qrr, kbuf, vT, rbuf, av);
  gemmO_kernel<<<dim3(512), dim3(256), 0, stream>>>(av, Wh + OFF_OUTW, Bf, out);
}